// Round 5
// baseline (5531.820 us; speedup 1.0000x reference)
//
#include <hip/hip_runtime.h>
#include <math.h>

// TrajectoryLSTM — R17: R16 resubmitted verbatim (R16 failed at container
// acquisition — infra flake, no kernel execution; JSON had no timing fields).
//  Design (R16): fused decode at 2 blocks/CU with full 128-VGPR budget.
//  R15 post-mortem: launch_bounds(1024,4) forced VGPR 64 -> spills (FETCH
//  541MB->2.23GB). R14 showed dec is traffic*BW limited (1.6GB @ 734GB/s).
//  512 blocks x 512 thr, 2 blocks/CU (LDS 71.9KB<80KB, launch_bounds(512,4)
//  -> VGPR cap 128 = R14's natural allocation, no spills). 2 blocks/CU gives
//  16 waves/CU AND cross-block overlap of the sync-separated tile pipeline.
//  Each block owns 256 rows = 4 tiles of 64 for all 12 steps.
//  Traffic cut: avalg lives in LDS across steps (block-private; d==0 reads the
//  enc-written global avalg). Software grid barrier unchanged (verified R14).
//  Numerics identical to verified R12/R14. k_prep/k_stats_mom/k_enc unchanged.

#define TT 8
#define PLEN 12
#define ROWS 64
#define DROWS 256   // rows per decode block (4 tiles of 64)
#define NBUCK 16
#define XSTR 104   // enc LDS plane stride (u16), verified R12
#define XSTR2 72   // dec tile plane stride (u16): 144B rows, 16B-aligned
#define VSTR 16    // v-plane stride (u16): 32B rows

typedef unsigned short u16;
typedef short short8 __attribute__((ext_vector_type(8)));
typedef float f4 __attribute__((ext_vector_type(4)));
union U8 { u16 u[8]; short8 v; };

// stats layout (doubles)
#define ST_ENCM 0                              // [NBUCK][8]  obs moments
#define ST_HP(d)  (128 + (d)*512)              // [NBUCK][32]
#define ST_MOM(d) (128 + PLEN*512 + (d)*128)   // [NBUCK][8]  lastpos moments
#define ST_TOTAL  (128 + PLEN*512 + PLEN*128)  // 7808

struct KP {
  const float *obs;
  const float *seW1,*seb1,*seg,*sebeta,*seW2,*seb2;
  const float *hpW1,*hpb1,*hpg,*hpbeta,*hpW2,*hpb2;
  const float *Wih,*Whh,*bih,*bhh;
  const int *xmax,*ymax;
  float *c,*lastpos,*avalg,*M,*gbias,*gbc;
  u16 *Xg1,*Xg2,*Xg3,*W1G,*W2G,*W3G,*H1G,*H2G,*H3G;
  double *stats;
  unsigned *bar;
  float *out;
  int B;
};

__device__ __forceinline__ float finv(float d){
  float r = __builtin_amdgcn_rcpf(d);
  return r*(2.f - d*r);
}
__device__ __forceinline__ float sigf(float x){
  float z = fminf(fmaxf(-x, -80.f), 80.f);
  return finv(1.f + __expf(z));
}
__device__ __forceinline__ float tanhf_(float x){
  float z = fminf(fmaxf(2.f*x, -80.f), 80.f);
  return 1.f - 2.f*finv(__expf(z) + 1.f);
}
__device__ __forceinline__ u16 f2bf(float x){
  union{float f; unsigned u;} v; v.f = x;
  unsigned r = v.u + 0x7FFFu + ((v.u >> 16) & 1u);
  return (u16)(r >> 16);
}
__device__ __forceinline__ float bf2f(u16 b){
  union{unsigned u; float f;} v; v.u = ((unsigned)b) << 16; return v.f;
}
__device__ __forceinline__ void split3(float x, u16& a, u16& b, u16& c){
  a = f2bf(x);
  float r1 = x - bf2f(a);
  b = f2bf(r1);
  float r2 = r1 - bf2f(b);
  c = f2bf(r2);
}
// agent-scope (device-coherent) double load — bypasses stale per-XCD L2
__device__ __forceinline__ double ald(const double* p){
  return __hip_atomic_load(p, __ATOMIC_RELAXED, __HIP_MEMORY_SCOPE_AGENT);
}

// software grid barrier: bar[0]=count, bar[1]=generation (sense)
__device__ __forceinline__ void grid_barrier(unsigned* bar, int tid){
  __threadfence();
  __syncthreads();
  if (tid == 0){
    unsigned gen = __hip_atomic_load(bar+1, __ATOMIC_RELAXED, __HIP_MEMORY_SCOPE_AGENT);
    unsigned a = __hip_atomic_fetch_add(bar, 1u, __ATOMIC_ACQ_REL, __HIP_MEMORY_SCOPE_AGENT);
    if (a == gridDim.x - 1u){
      __hip_atomic_store(bar, 0u, __ATOMIC_RELAXED, __HIP_MEMORY_SCOPE_AGENT);
      __hip_atomic_store(bar+1, gen+1u, __ATOMIC_RELEASE, __HIP_MEMORY_SCOPE_AGENT);
    } else {
      while (__hip_atomic_load(bar+1, __ATOMIC_ACQUIRE, __HIP_MEMORY_SCOPE_AGENT) == gen){
        __builtin_amdgcn_s_sleep(8);
      }
    }
  }
  __syncthreads();
}

// 6-product triple for one (A,B) k-chunk pair
#define MF6(A1c,A2c,A3c,b1,b2,b3,accv) \
  accv = __builtin_amdgcn_mfma_f32_16x16x32_bf16(A1c, b1, accv, 0,0,0); \
  accv = __builtin_amdgcn_mfma_f32_16x16x32_bf16(A1c, b2, accv, 0,0,0); \
  accv = __builtin_amdgcn_mfma_f32_16x16x32_bf16(A2c, b1, accv, 0,0,0); \
  accv = __builtin_amdgcn_mfma_f32_16x16x32_bf16(A2c, b2, accv, 0,0,0); \
  accv = __builtin_amdgcn_mfma_f32_16x16x32_bf16(A1c, b3, accv, 0,0,0); \
  accv = __builtin_amdgcn_mfma_f32_16x16x32_bf16(A3c, b1, accv, 0,0,0);

// se fold from 5 lastpos/obs moments (f64 exact): t = a*x + b*y + cb.
__device__ __forceinline__ void fold_se_mom(const KP& P, const double* stb, double N,
                                            float* sef, int tid){
  if (tid < 16){
    double Sx=0, Sy=0, Sxx=0, Syy=0, Sxy=0;
    for (int b = 0; b < NBUCK; ++b){
      const double* m = stb + b*8;
      Sx += ald(m+0); Sy += ald(m+1); Sxx += ald(m+2); Syy += ald(m+3); Sxy += ald(m+4);
    }
    double a = (double)P.seW1[2*tid], bb = (double)P.seW1[2*tid+1], cb = (double)P.seb1[tid];
    double S1 = a*Sx + bb*Sy + N*cb;
    double S2 = a*a*Sxx + bb*bb*Syy + 2.0*a*bb*Sxy + 2.0*a*cb*Sx + 2.0*bb*cb*Sy + N*cb*cb;
    double mu = S1/N, var = S2/N - mu*mu;
    float sc = rsqrtf((float)var + 1e-5f) * P.seg[tid];
    float sh = P.sebeta[tid] - (float)mu*sc;
    sef[tid]      = P.seW1[2*tid]*sc;
    sef[16 + tid] = P.seW1[2*tid+1]*sc;
    sef[32 + tid] = P.seb1[tid]*sc + sh;
  }
}

// Epilogue: lane's acc = gates i,f,g,o of (j=(2wid+ci)*4+q, r=rt*16+c).
template<int STR>
__device__ __forceinline__ void do_epilogue(f4 (&acc)[2][4], float (&cr)[2][4],
                                            u16* X1, u16* X2, u16* X3,
                                            bool first, int lane, int wid){
  const int c = lane & 15, q = lane >> 4;
  #pragma unroll
  for (int ci = 0; ci < 2; ++ci){
    const int j = (2*wid + ci)*4 + q;
    #pragma unroll
    for (int rt = 0; rt < 4; ++rt){
      const int r = rt*16 + c;
      float iv = acc[ci][rt].x, fv = acc[ci][rt].y;
      float gv = acc[ci][rt].z, ov = acc[ci][rt].w;
      float cp = first ? 0.f : cr[ci][rt];
      float cn = sigf(fv)*cp + sigf(iv)*tanhf_(gv);
      cr[ci][rt] = cn;
      float hn = sigf(ov)*tanhf_(cn);
      u16 a, b, cc2;
      split3(hn, a, b, cc2);
      X1[r*STR + j] = a; X2[r*STR + j] = b; X3[r*STR + j] = cc2;
    }
  }
}

// Post-step tail (enc): LDS planes -> global Xg, aval MFMA (waves 0..3),
// avalg write, hp stats -> bucketed f64 atomics.
template<int STR>
__device__ __forceinline__ void tail_xg_aval(const KP& P, long row0,
                                             const u16* X1, const u16* X2, const u16* X3,
                                             double* redd, double* st,
                                             int tid, int lane, int wid, int blk){
  {
    int r = tid >> 3, ch = tid & 7;
    *(short8*)&P.Xg1[(row0 + r)*64 + ch*8] = *(const short8*)&X1[r*STR + ch*8];
    *(short8*)&P.Xg2[(row0 + r)*64 + ch*8] = *(const short8*)&X2[r*STR + ch*8];
    *(short8*)&P.Xg3[(row0 + r)*64 + ch*8] = *(const short8*)&X3[r*STR + ch*8];
  }
  if (wid < 4){
    const int c = lane & 15, q = lane >> 4, rt = wid;
    f4 av = *(const f4*)&P.hpb1[q*4];
    #pragma unroll
    for (int kc = 0; kc < 2; ++kc){
      const int aoff = (lane & 15)*64 + kc*32 + q*8;
      short8 HA1 = *(const short8*)&P.H1G[aoff];
      short8 HA2 = *(const short8*)&P.H2G[aoff];
      short8 HA3 = *(const short8*)&P.H3G[aoff];
      const int boff = (rt*16 + c)*STR + kc*32 + q*8;
      short8 b1 = *(const short8*)&X1[boff];
      short8 b2 = *(const short8*)&X2[boff];
      short8 b3 = *(const short8*)&X3[boff];
      MF6(HA1, HA2, HA3, b1, b2, b3, av);
    }
    #pragma unroll
    for (int i = 0; i < 4; ++i)
      P.avalg[(long)(q*4 + i)*P.B + row0 + rt*16 + c] = av[i];
    #pragma unroll
    for (int i = 0; i < 4; ++i){
      double s = (double)av[i];
      double s2 = s*s;
      #pragma unroll
      for (int off = 8; off; off >>= 1){
        s  += __shfl_down(s,  off, 16);
        s2 += __shfl_down(s2, off, 16);
      }
      if (c == 0){
        redd[wid*32 + q*4 + i]      = s;
        redd[wid*32 + 16 + q*4 + i] = s2;
      }
    }
  }
  __syncthreads();
  if (tid < 32){
    double s = redd[tid] + redd[32 + tid] + redd[64 + tid] + redd[96 + tid];
    atomicAdd(&st[(blk & (NBUCK-1))*32 + tid], s);
  }
}

// --- k_prep (merged): M = Wih@seW2, gbias; then 3-way weight/hpW1 splits ---
__global__ __launch_bounds__(256) void k_prep(KP P){
  const int g = threadIdx.x;
  {
    const float* __restrict__ wr = P.Wih + g*64;
    double gb = (double)P.bih[g] + (double)P.bhh[g];
    for (int e = 0; e < 64; ++e) gb += (double)wr[e]*(double)P.seb2[e];
    P.gbias[g] = (float)gb;
    for (int q = 0; q < 16; ++q){
      double m = 0.0;
      for (int e = 0; e < 64; ++e) m += (double)wr[e]*(double)P.seW2[e*16+q];
      P.M[g*16+q] = (float)m;
    }
  }
  __syncthreads();
  {
    const int cidx = g, gate = cidx & 3, j = cidx >> 2;
    P.gbc[cidx] = P.gbias[gate*64 + j];
    for (int k = 0; k < 96; ++k){
      float w = 0.f;
      if (k < 64)      w = P.Whh[(gate*64 + j)*64 + k];
      else if (k < 80) w = P.M[(gate*64 + j)*16 + (k - 64)];
      u16 a, b, c;
      split3(w, a, b, c);
      P.W1G[cidx*96 + k] = a;
      P.W2G[cidx*96 + k] = b;
      P.W3G[cidx*96 + k] = c;
    }
    if (cidx < 16){
      for (int k = 0; k < 64; ++k){
        u16 a, b, c;
        split3(P.hpW1[cidx*64 + k], a, b, c);
        P.H1G[cidx*64 + k] = a;
        P.H2G[cidx*64 + k] = b;
        P.H3G[cidx*64 + k] = c;
      }
    }
  }
}

// --- obs 5-moment stats over T*B ---
__global__ __launch_bounds__(512) void k_stats_mom(KP P){
  __shared__ double redd[5*9];
  const int tid = threadIdx.x, lane = tid & 63, wid = tid >> 6;
  const int row = blockIdx.x*512 + tid;
  const int B = P.B;
  const float xm = (float)P.xmax[0], ym = (float)P.ymax[0];
  double sx=0, sy=0, sxx=0, syy=0, sxy=0;
  #pragma unroll 1
  for (int t = 0; t < TT; ++t){
    float2 o = ((const float2*)P.obs)[(long)t*B + row];
    float x = o.x/xm, y = o.y/ym;
    sx += (double)x; sy += (double)y;
    sxx += (double)x*(double)x; syy += (double)y*(double)y;
    sxy += (double)x*(double)y;
  }
  #pragma unroll
  for (int off = 32; off; off >>= 1){
    sx  += __shfl_down(sx,  off, 64);
    sy  += __shfl_down(sy,  off, 64);
    sxx += __shfl_down(sxx, off, 64);
    syy += __shfl_down(syy, off, 64);
    sxy += __shfl_down(sxy, off, 64);
  }
  if (lane == 0){
    redd[0*9+wid]=sx; redd[1*9+wid]=sy; redd[2*9+wid]=sxx;
    redd[3*9+wid]=syy; redd[4*9+wid]=sxy;
  }
  __syncthreads();
  if (tid < 5){
    double s = 0.0;
    for (int w = 0; w < 8; ++w) s += redd[tid*9 + w];
    atomicAdd(&P.stats[ST_ENCM + (blockIdx.x & (NBUCK-1))*8 + tid], s);
  }
}

// --- k_enc: 8 encode steps; A-frags register-resident; unchanged from R12 ---
__global__ __launch_bounds__(512) void k_enc(KP P){
  __shared__ __align__(16) u16 X1[ROWS*XSTR];
  __shared__ __align__(16) u16 X2[ROWS*XSTR];
  __shared__ __align__(16) u16 X3[ROWS*XSTR];
  __shared__ float sef[48];
  __shared__ double redd[128];
  const int tid = threadIdx.x, lane = tid & 63, wid = tid >> 6;
  const int B = P.B;
  const long row0 = (long)blockIdx.x * ROWS;
  const float xm = (float)P.xmax[0], ym = (float)P.ymax[0];
  const int c = lane & 15, q = lane >> 4;

  short8 A1r[2][3], A2r[2][3], A3r[2][3];
  f4 biasr[2];
  #pragma unroll
  for (int ci = 0; ci < 2; ++ci){
    const int crow = (2*wid + ci)*16 + c;
    #pragma unroll
    for (int kc = 0; kc < 3; ++kc){
      const int aoff = crow*96 + kc*32 + q*8;
      A1r[ci][kc] = *(const short8*)&P.W1G[aoff];
      A2r[ci][kc] = *(const short8*)&P.W2G[aoff];
      A3r[ci][kc] = *(const short8*)&P.W3G[aoff];
    }
    biasr[ci] = *(const f4*)&P.gbc[(2*wid + ci)*16 + q*4];
  }

  for (int m = tid; m < (ROWS*XSTR)/2; m += 512){
    ((unsigned*)X1)[m] = 0u; ((unsigned*)X2)[m] = 0u; ((unsigned*)X3)[m] = 0u;
  }
  fold_se_mom(P, P.stats + ST_ENCM, 8.0*(double)B, sef, tid);
  __syncthreads();

  if (tid < ROWS){
    float2 o = ((const float2*)P.obs)[row0 + tid];
    float p0 = o.x/xm, p1 = o.y/ym;
    #pragma unroll
    for (int qq = 0; qq < 16; ++qq){
      float tv = sef[qq]*p0 + sef[16+qq]*p1 + sef[32+qq];
      tv = tv > 0.f ? tv : 0.f;
      u16 a, b, cc;
      split3(tv, a, b, cc);
      X1[tid*XSTR + 64 + qq] = a; X2[tid*XSTR + 64 + qq] = b; X3[tid*XSTR + 64 + qq] = cc;
    }
  }
  __syncthreads();

  float cr[2][4];
  f4 acc[2][4];

  #pragma unroll 1
  for (int t = 0; t < TT; ++t){
    #pragma unroll
    for (int ci = 0; ci < 2; ++ci)
      #pragma unroll
      for (int rt = 0; rt < 4; ++rt) acc[ci][rt] = biasr[ci];
    #pragma unroll
    for (int rt = 0; rt < 4; ++rt){
      #pragma unroll
      for (int kc = 0; kc < 3; ++kc){
        const int boff = (rt*16 + c)*XSTR + kc*32 + q*8;
        short8 b1 = *(const short8*)&X1[boff];
        short8 b2 = *(const short8*)&X2[boff];
        short8 b3 = *(const short8*)&X3[boff];
        #pragma unroll
        for (int ci = 0; ci < 2; ++ci){
          MF6(A1r[ci][kc], A2r[ci][kc], A3r[ci][kc], b1, b2, b3, acc[ci][rt]);
        }
      }
    }
    __syncthreads();
    do_epilogue<XSTR>(acc, cr, X1, X2, X3, t == 0, lane, wid);
    if (t < TT-1 && tid < ROWS){
      float2 o = ((const float2*)P.obs)[(long)(t+1)*B + row0 + tid];
      float p0 = o.x/xm, p1 = o.y/ym;
      #pragma unroll
      for (int qq = 0; qq < 16; ++qq){
        float tv = sef[qq]*p0 + sef[16+qq]*p1 + sef[32+qq];
        tv = tv > 0.f ? tv : 0.f;
        u16 a, b, cc;
        split3(tv, a, b, cc);
        X1[tid*XSTR + 64 + qq] = a; X2[tid*XSTR + 64 + qq] = b; X3[tid*XSTR + 64 + qq] = cc;
      }
    }
    __syncthreads();
  }

  #pragma unroll
  for (int ci = 0; ci < 2; ++ci){
    const int j = (2*wid + ci)*4 + q;
    #pragma unroll
    for (int rt = 0; rt < 4; ++rt)
      P.c[(long)j*B + row0 + rt*16 + c] = cr[ci][rt];
  }
  tail_xg_aval<XSTR>(P, row0, X1, X2, X3, redd, P.stats + ST_HP(0), tid, lane, wid, blockIdx.x);
}

// --- k_dec_fused: all 12 decode steps, plain launch + software grid barrier.
//     512 blocks x 512 thr, 2 blocks/CU. Block owns rows [row0, row0+256)
//     as 4 tiles of 64; avalg block-private in LDS across steps.
__global__ __launch_bounds__(512, 4) void k_dec_fused(KP P){
  __shared__ __align__(16) u16 Xt1[ROWS*XSTR2];
  __shared__ __align__(16) u16 Xt2[ROWS*XSTR2];
  __shared__ __align__(16) u16 Xt3[ROWS*XSTR2];
  __shared__ __align__(16) u16 V1[DROWS*VSTR];
  __shared__ __align__(16) u16 V2[DROWS*VSTR];
  __shared__ __align__(16) u16 V3[DROWS*VSTR];
  __shared__ float avls[16*DROWS];   // aval, block-private across steps
  __shared__ float2 lp[DROWS];
  __shared__ float sef[48];
  __shared__ double redd[128];

  const int tid = threadIdx.x, lane = tid & 63, wid = tid >> 6;
  const int B = P.B;
  const long row0 = (long)blockIdx.x * DROWS;
  const int c = lane & 15, q = lane >> 4;
  const float xm = (float)P.xmax[0], ym = (float)P.ymax[0];

  // hoisted weight A-fragments (planes 1,2) + gate bias (step-invariant)
  short8 A1r[2][3], A2r[2][3];
  f4 biasr[2];
  #pragma unroll
  for (int ci = 0; ci < 2; ++ci){
    const int crow = (2*wid + ci)*16 + c;
    #pragma unroll
    for (int kc = 0; kc < 3; ++kc){
      const int aoff = crow*96 + kc*32 + q*8;
      A1r[ci][kc] = *(const short8*)&P.W1G[aoff];
      A2r[ci][kc] = *(const short8*)&P.W2G[aoff];
    }
    biasr[ci] = *(const f4*)&P.gbc[(2*wid + ci)*16 + q*4];
  }

  #pragma unroll 1
  for (int d = 0; d < PLEN; ++d){
    // ---------- pos phase (256 rows, threads 0..255) ----------
    if (tid < 16){
      const double* st = P.stats + ST_HP(d);
      double s = 0.0, s2 = 0.0;
      for (int b = 0; b < NBUCK; ++b){ s += ald(&st[b*32 + tid]); s2 += ald(&st[b*32 + 16 + tid]); }
      double invN = 1.0/(double)B;
      double mu = s*invN, var = s2*invN - mu*mu;
      float sc = rsqrtf((float)var + 1e-5f) * P.hpg[tid];
      sef[tid] = sc;
      sef[16+tid] = P.hpbeta[tid] - (float)mu*sc;
    }
    __syncthreads();
    double a0=0.0, a1=0.0, a2=0.0, a3=0.0, a4=0.0;
    if (tid < DROWS){
      const long row = row0 + tid;
      float r0v = P.hpb2[0], r1v = P.hpb2[1];
      #pragma unroll
      for (int qq = 0; qq < 16; ++qq){
        float a = (d == 0) ? P.avalg[(long)qq*B + row] : avls[qq*DROWS + tid];
        a = a*sef[qq] + sef[16+qq];
        a = a > 0.f ? a : 0.f;
        r0v += a*P.hpW2[qq]; r1v += a*P.hpW2[16+qq];
      }
      float l0, l1;
      if (d == 0){
        float2 o = ((const float2*)P.obs)[(long)(TT-1)*B + row];
        l0 = o.x/xm; l1 = o.y/ym;
      } else {
        float2 t = lp[tid]; l0 = t.x; l1 = t.y;
      }
      l0 = sigf(r0v + l0);
      l1 = sigf(r1v + l1);
      lp[tid] = make_float2(l0, l1);
      ((float2*)P.out)[(long)d*B + row] = make_float2(l0*xm, l1*ym);
      a0 = l0; a1 = l1;
      a2 = (double)l0*(double)l0; a3 = (double)l1*(double)l1; a4 = (double)l0*(double)l1;
    }
    #pragma unroll
    for (int off = 32; off; off >>= 1){
      a0 += __shfl_down(a0, off, 64); a1 += __shfl_down(a1, off, 64);
      a2 += __shfl_down(a2, off, 64); a3 += __shfl_down(a3, off, 64);
      a4 += __shfl_down(a4, off, 64);
    }
    if (lane == 0){
      redd[0*9+wid]=a0; redd[1*9+wid]=a1; redd[2*9+wid]=a2;
      redd[3*9+wid]=a3; redd[4*9+wid]=a4;
    }
    __syncthreads();
    if (tid < 5){
      double s = 0.0;
      #pragma unroll
      for (int w = 0; w < 8; ++w) s += redd[tid*9 + w];
      atomicAdd(&P.stats[ST_MOM(d) + (blockIdx.x & (NBUCK-1))*8 + tid], s);
    }
    if (d == PLEN-1) break;
    grid_barrier(P.bar, tid);

    // ---------- lstm phase ----------
    fold_se_mom(P, P.stats + ST_MOM(d), (double)B, sef, tid);
    __syncthreads();
    // v-planes: se embedding of lastpos for all 256 own rows
    if (tid < DROWS){
      float2 l = lp[tid];
      U8 u1a, u1b, u2a, u2b, u3a, u3b;
      #pragma unroll
      for (int ch = 0; ch < 8; ++ch){
        float tv = sef[ch]*l.x + sef[16+ch]*l.y + sef[32+ch];
        tv = tv > 0.f ? tv : 0.f;
        split3(tv, u1a.u[ch], u2a.u[ch], u3a.u[ch]);
      }
      #pragma unroll
      for (int ch = 8; ch < 16; ++ch){
        float tv = sef[ch]*l.x + sef[16+ch]*l.y + sef[32+ch];
        tv = tv > 0.f ? tv : 0.f;
        split3(tv, u1b.u[ch-8], u2b.u[ch-8], u3b.u[ch-8]);
      }
      *(short8*)&V1[tid*VSTR]     = u1a.v;
      *(short8*)&V1[tid*VSTR + 8] = u1b.v;
      *(short8*)&V2[tid*VSTR]     = u2a.v;
      *(short8*)&V2[tid*VSTR + 8] = u2b.v;
      *(short8*)&V3[tid*VSTR]     = u3a.v;
      *(short8*)&V3[tid*VSTR + 8] = u3b.v;
    }
    __syncthreads();

    #pragma unroll 1
    for (int tile = 0; tile < DROWS/ROWS; ++tile){
      const int lrow0 = tile*ROWS;                 // block-local first row of tile
      const long trow0 = row0 + lrow0;
      // stage h planes: Xg (written by own tail last step / enc) -> LDS, coalesced
      {
        const int r = tid >> 3, ch = tid & 7;
        *(short8*)&Xt1[r*XSTR2 + ch*8] = *(const short8*)&P.Xg1[(trow0 + r)*64 + ch*8];
        *(short8*)&Xt2[r*XSTR2 + ch*8] = *(const short8*)&P.Xg2[(trow0 + r)*64 + ch*8];
        *(short8*)&Xt3[r*XSTR2 + ch*8] = *(const short8*)&P.Xg3[(trow0 + r)*64 + ch*8];
      }
      // c state for this tile
      float crt[2][4];
      #pragma unroll
      for (int ci = 0; ci < 2; ++ci){
        const int j = (2*wid + ci)*4 + q;
        #pragma unroll
        for (int rt = 0; rt < 4; ++rt)
          crt[ci][rt] = P.c[(long)j*B + trow0 + rt*16 + c];
      }
      __syncthreads();

      // gate GEMM: kc=0,1 h from LDS; kc=2 v from v-planes; A3 streamed from L2
      f4 acc[2][4];
      #pragma unroll
      for (int ci = 0; ci < 2; ++ci)
        #pragma unroll
        for (int rt = 0; rt < 4; ++rt) acc[ci][rt] = biasr[ci];
      #pragma unroll
      for (int rt = 0; rt < 4; ++rt){
        #pragma unroll
        for (int kc = 0; kc < 2; ++kc){
          const int boff = (rt*16 + c)*XSTR2 + kc*32 + q*8;
          short8 b1 = *(const short8*)&Xt1[boff];
          short8 b2 = *(const short8*)&Xt2[boff];
          short8 b3 = *(const short8*)&Xt3[boff];
          #pragma unroll
          for (int ci = 0; ci < 2; ++ci){
            short8 A3 = *(const short8*)&P.W3G[((2*wid + ci)*16 + c)*96 + kc*32 + q*8];
            MF6(A1r[ci][kc], A2r[ci][kc], A3, b1, b2, b3, acc[ci][rt]);
          }
        }
        short8 vb1 = {0,0,0,0,0,0,0,0}, vb2 = vb1, vb3 = vb1;
        if (q < 2){
          const int voff = (lrow0 + rt*16 + c)*VSTR + q*8;
          vb1 = *(const short8*)&V1[voff];
          vb2 = *(const short8*)&V2[voff];
          vb3 = *(const short8*)&V3[voff];
        }
        #pragma unroll
        for (int ci = 0; ci < 2; ++ci){
          short8 A3 = *(const short8*)&P.W3G[((2*wid + ci)*16 + c)*96 + 64 + q*8];
          MF6(A1r[ci][2], A2r[ci][2], A3, vb1, vb2, vb3, acc[ci][rt]);
        }
      }
      __syncthreads();

      // epilogue: new c (regs->global), split-h -> LDS planes
      do_epilogue<XSTR2>(acc, crt, Xt1, Xt2, Xt3, false, lane, wid);
      #pragma unroll
      for (int ci = 0; ci < 2; ++ci){
        const int j = (2*wid + ci)*4 + q;
        #pragma unroll
        for (int rt = 0; rt < 4; ++rt)
          P.c[(long)j*B + trow0 + rt*16 + c] = crt[ci][rt];
      }
      __syncthreads();

      // tail: LDS -> Xg (coalesced), aval MFMA (waves 0..3) -> avls, stats
      {
        const int r = tid >> 3, ch = tid & 7;
        *(short8*)&P.Xg1[(trow0 + r)*64 + ch*8] = *(const short8*)&Xt1[r*XSTR2 + ch*8];
        *(short8*)&P.Xg2[(trow0 + r)*64 + ch*8] = *(const short8*)&Xt2[r*XSTR2 + ch*8];
        *(short8*)&P.Xg3[(trow0 + r)*64 + ch*8] = *(const short8*)&Xt3[r*XSTR2 + ch*8];
      }
      if (wid < 4){
        const int rt = wid;
        f4 av = *(const f4*)&P.hpb1[q*4];
        #pragma unroll
        for (int kc = 0; kc < 2; ++kc){
          const int aoff = (lane & 15)*64 + kc*32 + q*8;
          short8 HA1 = *(const short8*)&P.H1G[aoff];
          short8 HA2 = *(const short8*)&P.H2G[aoff];
          short8 HA3 = *(const short8*)&P.H3G[aoff];
          const int boff = (rt*16 + c)*XSTR2 + kc*32 + q*8;
          short8 b1 = *(const short8*)&Xt1[boff];
          short8 b2 = *(const short8*)&Xt2[boff];
          short8 b3 = *(const short8*)&Xt3[boff];
          MF6(HA1, HA2, HA3, b1, b2, b3, av);
        }
        #pragma unroll
        for (int i = 0; i < 4; ++i)
          avls[(q*4 + i)*DROWS + lrow0 + rt*16 + c] = av[i];
        #pragma unroll
        for (int i = 0; i < 4; ++i){
          double s = (double)av[i], s2 = s*s;
          #pragma unroll
          for (int off = 8; off; off >>= 1){
            s  += __shfl_down(s,  off, 16);
            s2 += __shfl_down(s2, off, 16);
          }
          if (c == 0){
            redd[wid*32 + q*4 + i]      = s;
            redd[wid*32 + 16 + q*4 + i] = s2;
          }
        }
      }
      __syncthreads();
      if (tid < 32){
        double s = redd[tid] + redd[32 + tid] + redd[64 + tid] + redd[96 + tid];
        atomicAdd(&P.stats[ST_HP(d+1) + (blockIdx.x & (NBUCK-1))*32 + tid], s);
      }
      __syncthreads();
    }
    grid_barrier(P.bar, tid);
  }
}

extern "C" void kernel_launch(void* const* d_in, const int* in_sizes, int n_in,
                              void* d_out, int out_size, void* d_ws, size_t ws_size,
                              hipStream_t stream){
  KP P;
  P.obs    = (const float*)d_in[0];
  P.seW1   = (const float*)d_in[1];
  P.seb1   = (const float*)d_in[2];
  P.seg    = (const float*)d_in[3];
  P.sebeta = (const float*)d_in[4];
  P.seW2   = (const float*)d_in[5];
  P.seb2   = (const float*)d_in[6];
  P.hpW1   = (const float*)d_in[7];
  P.hpb1   = (const float*)d_in[8];
  P.hpg    = (const float*)d_in[9];
  P.hpbeta = (const float*)d_in[10];
  P.hpW2   = (const float*)d_in[11];
  P.hpb2   = (const float*)d_in[12];
  P.Wih    = (const float*)d_in[13];
  P.Whh    = (const float*)d_in[14];
  P.bih    = (const float*)d_in[15];
  P.bhh    = (const float*)d_in[16];
  P.xmax   = (const int*)d_in[17];
  P.ymax   = (const int*)d_in[18];
  // d_in[19] = pred_len (fixed 12)

  const int B = in_sizes[0] / (TT*2);   // 131072
  P.B = B;
  float* ws = (float*)d_ws;
  // float-slot offsets. Xg plane = B*64 u16 = 32B float-slots. ~93.6 MB total.
  P.Xg1     = (u16*)(ws);
  P.Xg2     = (u16*)(ws + (size_t)32*B);
  P.c       = ws + (size_t)64*B;                   // [64][B] f32
  P.lastpos = ws + (size_t)128*B;                  // [B][2] (unused in R17)
  P.Xg3     = (u16*)(ws + (size_t)130*B);
  P.avalg   = ws + (size_t)162*B;                  // [16][B] (enc->dec d=0 only)
  float* tail = ws + (size_t)178*B;
  P.M     = tail;                          // 4096
  P.gbias = tail + 4096;                   // 256
  P.gbc   = tail + 4352;                   // 256
  // W planes: 256*96 u16 = 12288 float-slots each
  P.W1G   = (u16*)(tail + 4608);
  P.W2G   = (u16*)(tail + 4608 + 12288);
  P.W3G   = (u16*)(tail + 4608 + 24576);
  // H planes: 16*64 u16 = 512 float-slots each
  P.H1G   = (u16*)(tail + 4608 + 36864);
  P.H2G   = (u16*)(tail + 4608 + 37376);
  P.H3G   = (u16*)(tail + 4608 + 37888);
  P.stats = (double*)(tail + 4608 + 38400);  // 7808 doubles
  P.bar   = (unsigned*)(P.stats + ST_TOTAL); // 2 uints (barrier count/gen)
  P.out   = (float*)d_out;

  hipMemsetAsync(P.stats, 0, ST_TOTAL*sizeof(double) + 16, stream);

  k_prep     <<<1, 256, 0, stream>>>(P);
  k_stats_mom<<<B/512, 512, 0, stream>>>(P);
  k_enc      <<<B/ROWS, 512, 0, stream>>>(P);
  k_dec_fused<<<B/DROWS, 512, 0, stream>>>(P);
}

// Round 9
// 1562.556 us; speedup vs baseline: 3.5402x; 3.5402x over previous
//
#include <hip/hip_runtime.h>
#include <math.h>

// TrajectoryLSTM — R21: back to the VERIFIED R12 structure (1853 us, no grid
// barrier) + one surgical fix.
//  R18-R20 post-mortem: those weren't infra flakes — measured occupancy law
//  (k_enc 112VGPR->8 waves/CU; R14 128VGPR->8; R17 64VGPR->16) means the
//  (512,2)/128-VGPR fused kernel got 1 block/CU -> only 256/512 blocks
//  co-resident -> software grid barrier DEADLOCK -> harness timeout ("Trio
//  nursery", no timing fields). Fusion is structurally cornered: 16 waves/CU
//  needs <=64 VGPR (spills, R17 disaster); 8-wave fusion measured 2189 us
//  (R14) < non-fused 1455 us decode.
//  R21 change vs R12: k_dec_lstm stages Xg->LDS once per block (coalesced)
//  and reads b-frags from LDS instead of 128B-stride scattered global reads
//  that every one of the 8 waves repeated (8x L2 re-read). X planes were
//  already allocated (epilogue use); staged region is fully overwritten by
//  the epilogue, with syncs added for the RAW/WAR hazards. A-frags stay
//  streamed (hoisting triggers the 8-wave occupancy cliff).
//  All numerics identical to verified R12.

#define TT 8
#define PLEN 12
#define ROWS 64
#define NBUCK 16
#define XSTR 104   // LDS transpose-plane row stride (u16); 16B-aligned rows

typedef unsigned short u16;
typedef short short8 __attribute__((ext_vector_type(8)));
typedef float f4 __attribute__((ext_vector_type(4)));
union U8 { u16 u[8]; short8 v; };

// stats layout (doubles)
#define ST_ENCM 0                              // [NBUCK][8]  obs moments
#define ST_HP(d)  (128 + (d)*512)              // [NBUCK][32]
#define ST_MOM(d) (128 + PLEN*512 + (d)*128)   // [NBUCK][8]  lastpos moments
#define ST_TOTAL  (128 + PLEN*512 + PLEN*128)  // 7808

struct KP {
  const float *obs;
  const float *seW1,*seb1,*seg,*sebeta,*seW2,*seb2;
  const float *hpW1,*hpb1,*hpg,*hpbeta,*hpW2,*hpb2;
  const float *Wih,*Whh,*bih,*bhh;
  const int *xmax,*ymax;
  float *c,*lastpos,*avalg,*M,*gbias,*gbc;
  u16 *Xg1,*Xg2,*Xg3,*W1G,*W2G,*W3G,*H1G,*H2G,*H3G;
  double *stats;
  float *out;
  int B;
};

__device__ __forceinline__ float finv(float d){
  float r = __builtin_amdgcn_rcpf(d);
  return r*(2.f - d*r);
}
__device__ __forceinline__ float sigf(float x){
  float z = fminf(fmaxf(-x, -80.f), 80.f);
  return finv(1.f + __expf(z));
}
__device__ __forceinline__ float tanhf_(float x){
  float z = fminf(fmaxf(2.f*x, -80.f), 80.f);
  return 1.f - 2.f*finv(__expf(z) + 1.f);
}
__device__ __forceinline__ u16 f2bf(float x){
  union{float f; unsigned u;} v; v.f = x;
  unsigned r = v.u + 0x7FFFu + ((v.u >> 16) & 1u);
  return (u16)(r >> 16);
}
__device__ __forceinline__ float bf2f(u16 b){
  union{unsigned u; float f;} v; v.u = ((unsigned)b) << 16; return v.f;
}
__device__ __forceinline__ void split3(float x, u16& a, u16& b, u16& c){
  a = f2bf(x);
  float r1 = x - bf2f(a);
  b = f2bf(r1);
  float r2 = r1 - bf2f(b);
  c = f2bf(r2);
}

// 6-product triple for one (A,B) k-chunk pair
#define MF6(A1c,A2c,A3c,b1,b2,b3,accv) \
  accv = __builtin_amdgcn_mfma_f32_16x16x32_bf16(A1c, b1, accv, 0,0,0); \
  accv = __builtin_amdgcn_mfma_f32_16x16x32_bf16(A1c, b2, accv, 0,0,0); \
  accv = __builtin_amdgcn_mfma_f32_16x16x32_bf16(A2c, b1, accv, 0,0,0); \
  accv = __builtin_amdgcn_mfma_f32_16x16x32_bf16(A2c, b2, accv, 0,0,0); \
  accv = __builtin_amdgcn_mfma_f32_16x16x32_bf16(A1c, b3, accv, 0,0,0); \
  accv = __builtin_amdgcn_mfma_f32_16x16x32_bf16(A3c, b1, accv, 0,0,0);

// se fold from 5 lastpos/obs moments (f64 exact): t = a*x + b*y + cb.
__device__ __forceinline__ void fold_se_mom(const KP& P, const double* stb, double N,
                                            float* sef, int tid){
  if (tid < 16){
    double Sx=0, Sy=0, Sxx=0, Syy=0, Sxy=0;
    for (int b = 0; b < NBUCK; ++b){
      const double* m = stb + b*8;
      Sx += m[0]; Sy += m[1]; Sxx += m[2]; Syy += m[3]; Sxy += m[4];
    }
    double a = (double)P.seW1[2*tid], bb = (double)P.seW1[2*tid+1], cb = (double)P.seb1[tid];
    double S1 = a*Sx + bb*Sy + N*cb;
    double S2 = a*a*Sxx + bb*bb*Syy + 2.0*a*bb*Sxy + 2.0*a*cb*Sx + 2.0*bb*cb*Sy + N*cb*cb;
    double mu = S1/N, var = S2/N - mu*mu;
    float sc = rsqrtf((float)var + 1e-5f) * P.seg[tid];
    float sh = P.sebeta[tid] - (float)mu*sc;
    sef[tid]      = P.seW1[2*tid]*sc;
    sef[16 + tid] = P.seW1[2*tid+1]*sc;
    sef[32 + tid] = P.seb1[tid]*sc + sh;
  }
}

// Epilogue: lane's acc = gates i,f,g,o of (j=(2wid+ci)*4+q, r=rt*16+c).
__device__ __forceinline__ void do_epilogue(f4 (&acc)[2][4], float (&cr)[2][4],
                                            u16* X1, u16* X2, u16* X3,
                                            bool first, int lane, int wid){
  const int c = lane & 15, q = lane >> 4;
  #pragma unroll
  for (int ci = 0; ci < 2; ++ci){
    const int j = (2*wid + ci)*4 + q;
    #pragma unroll
    for (int rt = 0; rt < 4; ++rt){
      const int r = rt*16 + c;
      float iv = acc[ci][rt].x, fv = acc[ci][rt].y;
      float gv = acc[ci][rt].z, ov = acc[ci][rt].w;
      float cp = first ? 0.f : cr[ci][rt];
      float cn = sigf(fv)*cp + sigf(iv)*tanhf_(gv);
      cr[ci][rt] = cn;
      float hn = sigf(ov)*tanhf_(cn);
      u16 a, b, cc2;
      split3(hn, a, b, cc2);
      X1[r*XSTR + j] = a; X2[r*XSTR + j] = b; X3[r*XSTR + j] = cc2;
    }
  }
}

// Post-step tail: LDS planes -> global Xg (coalesced), aval MFMA (waves 0..3),
// avalg write, hp stats -> bucketed f64 atomics.
__device__ __forceinline__ void tail_xg_aval(const KP& P, long row0,
                                             const u16* X1, const u16* X2, const u16* X3,
                                             double* redd, double* st,
                                             int tid, int lane, int wid, int blk){
  {
    int r = tid >> 3, ch = tid & 7;
    *(short8*)&P.Xg1[(row0 + r)*64 + ch*8] = *(const short8*)&X1[r*XSTR + ch*8];
    *(short8*)&P.Xg2[(row0 + r)*64 + ch*8] = *(const short8*)&X2[r*XSTR + ch*8];
    *(short8*)&P.Xg3[(row0 + r)*64 + ch*8] = *(const short8*)&X3[r*XSTR + ch*8];
  }
  if (wid < 4){
    const int c = lane & 15, q = lane >> 4, rt = wid;
    f4 av = *(const f4*)&P.hpb1[q*4];
    #pragma unroll
    for (int kc = 0; kc < 2; ++kc){
      const int aoff = (lane & 15)*64 + kc*32 + q*8;
      short8 HA1 = *(const short8*)&P.H1G[aoff];
      short8 HA2 = *(const short8*)&P.H2G[aoff];
      short8 HA3 = *(const short8*)&P.H3G[aoff];
      const int boff = (rt*16 + c)*XSTR + kc*32 + q*8;
      short8 b1 = *(const short8*)&X1[boff];
      short8 b2 = *(const short8*)&X2[boff];
      short8 b3 = *(const short8*)&X3[boff];
      MF6(HA1, HA2, HA3, b1, b2, b3, av);
    }
    #pragma unroll
    for (int i = 0; i < 4; ++i)
      P.avalg[(long)(q*4 + i)*P.B + row0 + rt*16 + c] = av[i];
    #pragma unroll
    for (int i = 0; i < 4; ++i){
      double s = (double)av[i];
      double s2 = s*s;
      #pragma unroll
      for (int off = 8; off; off >>= 1){
        s  += __shfl_down(s,  off, 16);
        s2 += __shfl_down(s2, off, 16);
      }
      if (c == 0){
        redd[wid*32 + q*4 + i]      = s;
        redd[wid*32 + 16 + q*4 + i] = s2;
      }
    }
  }
  __syncthreads();
  if (tid < 32){
    double s = redd[tid] + redd[32 + tid] + redd[64 + tid] + redd[96 + tid];
    atomicAdd(&st[(blk & (NBUCK-1))*32 + tid], s);
  }
}

// --- k_prep (merged): M = Wih@seW2, gbias; then 3-way weight/hpW1 splits ---
__global__ __launch_bounds__(256) void k_prep(KP P){
  const int g = threadIdx.x;
  {
    const float* __restrict__ wr = P.Wih + g*64;
    double gb = (double)P.bih[g] + (double)P.bhh[g];
    for (int e = 0; e < 64; ++e) gb += (double)wr[e]*(double)P.seb2[e];
    P.gbias[g] = (float)gb;
    for (int q = 0; q < 16; ++q){
      double m = 0.0;
      for (int e = 0; e < 64; ++e) m += (double)wr[e]*(double)P.seW2[e*16+q];
      P.M[g*16+q] = (float)m;
    }
  }
  __syncthreads();
  {
    const int cidx = g, gate = cidx & 3, j = cidx >> 2;
    P.gbc[cidx] = P.gbias[gate*64 + j];
    for (int k = 0; k < 96; ++k){
      float w = 0.f;
      if (k < 64)      w = P.Whh[(gate*64 + j)*64 + k];
      else if (k < 80) w = P.M[(gate*64 + j)*16 + (k - 64)];
      u16 a, b, c;
      split3(w, a, b, c);
      P.W1G[cidx*96 + k] = a;
      P.W2G[cidx*96 + k] = b;
      P.W3G[cidx*96 + k] = c;
    }
    if (cidx < 16){
      for (int k = 0; k < 64; ++k){
        u16 a, b, c;
        split3(P.hpW1[cidx*64 + k], a, b, c);
        P.H1G[cidx*64 + k] = a;
        P.H2G[cidx*64 + k] = b;
        P.H3G[cidx*64 + k] = c;
      }
    }
  }
}

// --- obs 5-moment stats over T*B ---
__global__ __launch_bounds__(512) void k_stats_mom(KP P){
  __shared__ double redd[5*9];
  const int tid = threadIdx.x, lane = tid & 63, wid = tid >> 6;
  const int row = blockIdx.x*512 + tid;
  const int B = P.B;
  const float xm = (float)P.xmax[0], ym = (float)P.ymax[0];
  double sx=0, sy=0, sxx=0, syy=0, sxy=0;
  #pragma unroll 1
  for (int t = 0; t < TT; ++t){
    float2 o = ((const float2*)P.obs)[(long)t*B + row];
    float x = o.x/xm, y = o.y/ym;
    sx += (double)x; sy += (double)y;
    sxx += (double)x*(double)x; syy += (double)y*(double)y;
    sxy += (double)x*(double)y;
  }
  #pragma unroll
  for (int off = 32; off; off >>= 1){
    sx  += __shfl_down(sx,  off, 64);
    sy  += __shfl_down(sy,  off, 64);
    sxx += __shfl_down(sxx, off, 64);
    syy += __shfl_down(syy, off, 64);
    sxy += __shfl_down(sxy, off, 64);
  }
  if (lane == 0){
    redd[0*9+wid]=sx; redd[1*9+wid]=sy; redd[2*9+wid]=sxx;
    redd[3*9+wid]=syy; redd[4*9+wid]=sxy;
  }
  __syncthreads();
  if (tid < 5){
    double s = 0.0;
    for (int w = 0; w < 8; ++w) s += redd[tid*9 + w];
    atomicAdd(&P.stats[ST_ENCM + (blockIdx.x & (NBUCK-1))*8 + tid], s);
  }
}

// --- k_enc: 8 encode steps; A-frags REGISTER-RESIDENT across t-loop;
//     X planes LDS; c in regs; tail writes Xg + avalg + hp stats for d=0. ---
__global__ __launch_bounds__(512) void k_enc(KP P){
  __shared__ __align__(16) u16 X1[ROWS*XSTR];
  __shared__ __align__(16) u16 X2[ROWS*XSTR];
  __shared__ __align__(16) u16 X3[ROWS*XSTR];
  __shared__ float sef[48];
  __shared__ double redd[128];
  const int tid = threadIdx.x, lane = tid & 63, wid = tid >> 6;
  const int B = P.B;
  const long row0 = (long)blockIdx.x * ROWS;
  const float xm = (float)P.xmax[0], ym = (float)P.ymax[0];
  const int c = lane & 15, q = lane >> 4;

  // hoisted weight A-fragments + bias (step-invariant)
  short8 A1r[2][3], A2r[2][3], A3r[2][3];
  f4 biasr[2];
  #pragma unroll
  for (int ci = 0; ci < 2; ++ci){
    const int crow = (2*wid + ci)*16 + c;
    #pragma unroll
    for (int kc = 0; kc < 3; ++kc){
      const int aoff = crow*96 + kc*32 + q*8;
      A1r[ci][kc] = *(const short8*)&P.W1G[aoff];
      A2r[ci][kc] = *(const short8*)&P.W2G[aoff];
      A3r[ci][kc] = *(const short8*)&P.W3G[aoff];
    }
    biasr[ci] = *(const f4*)&P.gbc[(2*wid + ci)*16 + q*4];
  }

  for (int m = tid; m < (ROWS*XSTR)/2; m += 512){
    ((unsigned*)X1)[m] = 0u; ((unsigned*)X2)[m] = 0u; ((unsigned*)X3)[m] = 0u;
  }
  fold_se_mom(P, P.stats + ST_ENCM, 8.0*(double)B, sef, tid);
  __syncthreads();

  if (tid < ROWS){
    float2 o = ((const float2*)P.obs)[row0 + tid];
    float p0 = o.x/xm, p1 = o.y/ym;
    #pragma unroll
    for (int qq = 0; qq < 16; ++qq){
      float tv = sef[qq]*p0 + sef[16+qq]*p1 + sef[32+qq];
      tv = tv > 0.f ? tv : 0.f;
      u16 a, b, cc;
      split3(tv, a, b, cc);
      X1[tid*XSTR + 64 + qq] = a; X2[tid*XSTR + 64 + qq] = b; X3[tid*XSTR + 64 + qq] = cc;
    }
  }
  __syncthreads();

  float cr[2][4];
  f4 acc[2][4];

  #pragma unroll 1
  for (int t = 0; t < TT; ++t){
    #pragma unroll
    for (int ci = 0; ci < 2; ++ci)
      #pragma unroll
      for (int rt = 0; rt < 4; ++rt) acc[ci][rt] = biasr[ci];
    #pragma unroll
    for (int rt = 0; rt < 4; ++rt){
      #pragma unroll
      for (int kc = 0; kc < 3; ++kc){
        const int boff = (rt*16 + c)*XSTR + kc*32 + q*8;
        short8 b1 = *(const short8*)&X1[boff];
        short8 b2 = *(const short8*)&X2[boff];
        short8 b3 = *(const short8*)&X3[boff];
        #pragma unroll
        for (int ci = 0; ci < 2; ++ci){
          MF6(A1r[ci][kc], A2r[ci][kc], A3r[ci][kc], b1, b2, b3, acc[ci][rt]);
        }
      }
    }
    __syncthreads();
    do_epilogue(acc, cr, X1, X2, X3, t == 0, lane, wid);
    if (t < TT-1 && tid < ROWS){
      float2 o = ((const float2*)P.obs)[(long)(t+1)*B + row0 + tid];
      float p0 = o.x/xm, p1 = o.y/ym;
      #pragma unroll
      for (int qq = 0; qq < 16; ++qq){
        float tv = sef[qq]*p0 + sef[16+qq]*p1 + sef[32+qq];
        tv = tv > 0.f ? tv : 0.f;
        u16 a, b, cc;
        split3(tv, a, b, cc);
        X1[tid*XSTR + 64 + qq] = a; X2[tid*XSTR + 64 + qq] = b; X3[tid*XSTR + 64 + qq] = cc;
      }
    }
    __syncthreads();
  }

  #pragma unroll
  for (int ci = 0; ci < 2; ++ci){
    const int j = (2*wid + ci)*4 + q;
    #pragma unroll
    for (int rt = 0; rt < 4; ++rt)
      P.c[(long)j*B + row0 + rt*16 + c] = cr[ci][rt];
  }
  tail_xg_aval(P, row0, X1, X2, X3, redd, P.stats + ST_HP(0), tid, lane, wid, blockIdx.x);
}

// --- k_dec_pos: thin elementwise head from avalg (512 thr) ---
template<bool FIRSTD>
__global__ __launch_bounds__(512) void k_dec_pos(KP P, int d){
  __shared__ float hpf[32];
  __shared__ double redd[5*9];
  const int tid = threadIdx.x, lane = tid & 63, wid = tid >> 6;
  const int B = P.B;
  const int row = blockIdx.x*512 + tid;
  if (tid < 16){
    const double* st = P.stats + ST_HP(d);
    double s = 0.0, s2 = 0.0;
    for (int b = 0; b < NBUCK; ++b){ s += st[b*32 + tid]; s2 += st[b*32 + 16 + tid]; }
    double invN = 1.0/(double)B;
    double mu = s*invN, var = s2*invN - mu*mu;
    float sc = rsqrtf((float)var + 1e-5f) * P.hpg[tid];
    hpf[tid] = sc;
    hpf[16+tid] = P.hpbeta[tid] - (float)mu*sc;
  }
  __syncthreads();

  float r0v = P.hpb2[0], r1v = P.hpb2[1];
  #pragma unroll
  for (int qq = 0; qq < 16; ++qq){
    float a = P.avalg[(long)qq*B + row];
    a = a*hpf[qq] + hpf[16+qq];
    a = a > 0.f ? a : 0.f;
    r0v += a*P.hpW2[qq]; r1v += a*P.hpW2[16+qq];
  }
  const float xm = (float)P.xmax[0], ym = (float)P.ymax[0];
  float l0, l1;
  if constexpr (FIRSTD){
    float2 o = ((const float2*)P.obs)[(long)(TT-1)*B + row];
    l0 = o.x/xm; l1 = o.y/ym;
  } else {
    float2 lp = ((const float2*)P.lastpos)[row];
    l0 = lp.x; l1 = lp.y;
  }
  l0 = sigf(r0v + l0);
  l1 = sigf(r1v + l1);
  ((float2*)P.lastpos)[row] = make_float2(l0, l1);
  ((float2*)P.out)[(long)d*B + row] = make_float2(l0*xm, l1*ym);

  double a0=l0, a1=l1, a2=(double)l0*(double)l0, a3=(double)l1*(double)l1, a4=(double)l0*(double)l1;
  #pragma unroll
  for (int off = 32; off; off >>= 1){
    a0 += __shfl_down(a0, off, 64); a1 += __shfl_down(a1, off, 64);
    a2 += __shfl_down(a2, off, 64); a3 += __shfl_down(a3, off, 64);
    a4 += __shfl_down(a4, off, 64);
  }
  if (lane == 0){
    redd[0*9+wid]=a0; redd[1*9+wid]=a1; redd[2*9+wid]=a2;
    redd[3*9+wid]=a3; redd[4*9+wid]=a4;
  }
  __syncthreads();
  if (tid < 5){
    double s = 0.0;
    for (int w = 0; w < 8; ++w) s += redd[tid*9 + w];
    atomicAdd(&P.stats[ST_MOM(d) + (blockIdx.x & (NBUCK-1))*8 + tid], s);
  }
}

// --- k_dec_lstm: R21 change — Xg staged to LDS once per block (coalesced),
//     b-frags read via ds_read_b128 (was: 128B-stride scattered global reads,
//     repeated by all 8 waves). A-frags streamed from L2; v in-lane; c in regs.
template<int DUMMY>
__global__ __launch_bounds__(512) void k_dec_lstm(KP P, int d){
  __shared__ __align__(16) u16 X1[ROWS*XSTR];
  __shared__ __align__(16) u16 X2[ROWS*XSTR];
  __shared__ __align__(16) u16 X3[ROWS*XSTR];
  __shared__ float sef[48];
  __shared__ double redd[128];
  const int tid = threadIdx.x, lane = tid & 63, wid = tid >> 6;
  const int B = P.B;
  const long row0 = (long)blockIdx.x * ROWS;
  const int c = lane & 15, q = lane >> 4;

  fold_se_mom(P, P.stats + ST_MOM(d), (double)B, sef, tid);

  // stage h planes: Xg -> LDS, coalesced (each thread one short8 per plane)
  {
    const int r = tid >> 3, ch = tid & 7;
    *(short8*)&X1[r*XSTR + ch*8] = *(const short8*)&P.Xg1[(row0 + r)*64 + ch*8];
    *(short8*)&X2[r*XSTR + ch*8] = *(const short8*)&P.Xg2[(row0 + r)*64 + ch*8];
    *(short8*)&X3[r*XSTR + ch*8] = *(const short8*)&P.Xg3[(row0 + r)*64 + ch*8];
  }
  __syncthreads();   // sef + staged planes visible

  // in-lane v fragments for kc=2 (k=64..79 from lastpos; 80..95 zero)
  short8 vb1[4], vb2[4], vb3[4];
  {
    const short8 z = {0,0,0,0,0,0,0,0};
    #pragma unroll
    for (int rt = 0; rt < 4; ++rt){ vb1[rt] = z; vb2[rt] = z; vb3[rt] = z; }
    if (q < 2){
      #pragma unroll
      for (int rt = 0; rt < 4; ++rt){
        float2 lp = ((const float2*)P.lastpos)[row0 + rt*16 + c];
        U8 u1, u2, u3;
        #pragma unroll
        for (int j = 0; j < 8; ++j){
          const int ch = q*8 + j;
          float tv = sef[ch]*lp.x + sef[16+ch]*lp.y + sef[32+ch];
          tv = tv > 0.f ? tv : 0.f;
          split3(tv, u1.u[j], u2.u[j], u3.u[j]);
        }
        vb1[rt] = u1.v; vb2[rt] = u2.v; vb3[rt] = u3.v;
      }
    }
  }
  // prefetch c
  float cr[2][4];
  #pragma unroll
  for (int ci = 0; ci < 2; ++ci){
    const int j = (2*wid + ci)*4 + q;
    #pragma unroll
    for (int rt = 0; rt < 4; ++rt)
      cr[ci][rt] = P.c[(long)j*B + row0 + rt*16 + c];
  }

  // gate GEMM: h-part b-frags from LDS (ds_read_b128), A-frags streamed
  f4 acc[2][4];
  #pragma unroll
  for (int ci = 0; ci < 2; ++ci){
    f4 bias = *(const f4*)&P.gbc[(2*wid + ci)*16 + q*4];
    #pragma unroll
    for (int rt = 0; rt < 4; ++rt) acc[ci][rt] = bias;
  }
  #pragma unroll
  for (int rt = 0; rt < 4; ++rt){
    #pragma unroll
    for (int kc = 0; kc < 2; ++kc){
      const int boff = (rt*16 + c)*XSTR + kc*32 + q*8;
      short8 b1 = *(const short8*)&X1[boff];
      short8 b2 = *(const short8*)&X2[boff];
      short8 b3 = *(const short8*)&X3[boff];
      #pragma unroll
      for (int ci = 0; ci < 2; ++ci){
        const int aoff = ((2*wid + ci)*16 + c)*96 + kc*32 + q*8;
        short8 A1 = *(const short8*)&P.W1G[aoff];
        short8 A2 = *(const short8*)&P.W2G[aoff];
        short8 A3 = *(const short8*)&P.W3G[aoff];
        MF6(A1, A2, A3, b1, b2, b3, acc[ci][rt]);
      }
    }
    #pragma unroll
    for (int ci = 0; ci < 2; ++ci){
      const int aoff = ((2*wid + ci)*16 + c)*96 + 2*32 + q*8;
      short8 A1 = *(const short8*)&P.W1G[aoff];
      short8 A2 = *(const short8*)&P.W2G[aoff];
      short8 A3 = *(const short8*)&P.W3G[aoff];
      MF6(A1, A2, A3, vb1[rt], vb2[rt], vb3[rt], acc[ci][rt]);
    }
  }
  __syncthreads();   // all LDS b-frag reads complete before epilogue overwrite

  do_epilogue(acc, cr, X1, X2, X3, false, lane, wid);
  #pragma unroll
  for (int ci = 0; ci < 2; ++ci){
    const int j = (2*wid + ci)*4 + q;
    #pragma unroll
    for (int rt = 0; rt < 4; ++rt)
      P.c[(long)j*B + row0 + rt*16 + c] = cr[ci][rt];
  }
  __syncthreads();   // epilogue writes visible to tail
  tail_xg_aval(P, row0, X1, X2, X3, redd, P.stats + ST_HP(d+1), tid, lane, wid, blockIdx.x);
}

extern "C" void kernel_launch(void* const* d_in, const int* in_sizes, int n_in,
                              void* d_out, int out_size, void* d_ws, size_t ws_size,
                              hipStream_t stream){
  KP P;
  P.obs    = (const float*)d_in[0];
  P.seW1   = (const float*)d_in[1];
  P.seb1   = (const float*)d_in[2];
  P.seg    = (const float*)d_in[3];
  P.sebeta = (const float*)d_in[4];
  P.seW2   = (const float*)d_in[5];
  P.seb2   = (const float*)d_in[6];
  P.hpW1   = (const float*)d_in[7];
  P.hpb1   = (const float*)d_in[8];
  P.hpg    = (const float*)d_in[9];
  P.hpbeta = (const float*)d_in[10];
  P.hpW2   = (const float*)d_in[11];
  P.hpb2   = (const float*)d_in[12];
  P.Wih    = (const float*)d_in[13];
  P.Whh    = (const float*)d_in[14];
  P.bih    = (const float*)d_in[15];
  P.bhh    = (const float*)d_in[16];
  P.xmax   = (const int*)d_in[17];
  P.ymax   = (const int*)d_in[18];
  // d_in[19] = pred_len (fixed 12)

  const int B = in_sizes[0] / (TT*2);   // 131072
  P.B = B;
  float* ws = (float*)d_ws;
  // float-slot offsets. Xg plane = B*64 u16 = 32B float-slots. ~93.6 MB total.
  P.Xg1     = (u16*)(ws);
  P.Xg2     = (u16*)(ws + (size_t)32*B);
  P.c       = ws + (size_t)64*B;                   // [64][B] f32
  P.lastpos = ws + (size_t)128*B;                  // [B][2]
  P.Xg3     = (u16*)(ws + (size_t)130*B);
  P.avalg   = ws + (size_t)162*B;                  // [16][B]
  float* tail = ws + (size_t)178*B;
  P.M     = tail;                          // 4096
  P.gbias = tail + 4096;                   // 256
  P.gbc   = tail + 4352;                   // 256
  // W planes: 256*96 u16 = 12288 float-slots each
  P.W1G   = (u16*)(tail + 4608);
  P.W2G   = (u16*)(tail + 4608 + 12288);
  P.W3G   = (u16*)(tail + 4608 + 24576);
  // H planes: 16*64 u16 = 512 float-slots each
  P.H1G   = (u16*)(tail + 4608 + 36864);
  P.H2G   = (u16*)(tail + 4608 + 37376);
  P.H3G   = (u16*)(tail + 4608 + 37888);
  P.stats = (double*)(tail + 4608 + 38400);  // 7808 doubles
  P.out   = (float*)d_out;

  hipMemsetAsync(P.stats, 0, ST_TOTAL*sizeof(double), stream);

  k_prep     <<<1, 256, 0, stream>>>(P);
  k_stats_mom<<<B/512, 512, 0, stream>>>(P);
  k_enc      <<<B/ROWS, 512, 0, stream>>>(P);

  for (int d = 0; d < PLEN; ++d){
    if (d == 0) k_dec_pos<true ><<<B/512, 512, 0, stream>>>(P, d);
    else        k_dec_pos<false><<<B/512, 512, 0, stream>>>(P, d);
    if (d < PLEN-1) k_dec_lstm<0><<<B/ROWS, 512, 0, stream>>>(P, d);
  }
}